// Round 4
// baseline (93.611 us; speedup 1.0000x reference)
//
#include <hip/hip_runtime.h>

// Fused grouped 1x1 conv (q,k,v) + 5x5 reflect-window per-channel softmax attention.
// x: (2,128,96,96) f32; wq/wk/wv: (4,32,32) f32; out: (2,128,96,96) f32.
// Block = (8x8 tile, group, batch), 256 thr = 4 waves; wave owns 8 out-channels.
//
// R4: phase-1 staging now aligned float4 row loads (16 floats cover the 12-col
//     region; reflect halo columns fixed up in-LDS for edge tiles) -> each
//     global_load_dwordx4 moves 1024B in full 64B lines vs scattered 4B loads.
//     All bf16 conversions via (bits+0x8000)>>16 (1-2 VALU) instead of the
//     software-RNE __float2bfloat16 sequence; q pairs packed with v_perm_b32.
//     LDS 31872B (<=32KB) -> 5 blocks/CU, grid 1152 <= 1280 single round.

#define HW 96
#define RG 12
#define NPOS 144
#define KVSTR 145           // padded channel stride (dwords) for kv buffer

typedef short short8 __attribute__((ext_vector_type(8)));
typedef float float4v __attribute__((ext_vector_type(4)));

__device__ __forceinline__ int refl(int i) {
    i = (i < 0) ? -i : i;          // reflect (edge excluded): -1->1, -2->2
    i = (i > 95) ? (190 - i) : i;  // 96->94, 97->93
    return i;
}

// float -> bf16 bits, round-to-nearest (no tie-to-even; inputs are tame)
__device__ __forceinline__ unsigned int bfr(float f) {
    return (__float_as_uint(f) + 0x8000u) >> 16;
}

__global__ __launch_bounds__(256) void fused_attn(
    const float* __restrict__ x, const float* __restrict__ wq,
    const float* __restrict__ wk, const float* __restrict__ wv,
    float* __restrict__ out)
{
    __shared__ unsigned short xs[NPOS * 32];     // bf16 x, [pos][cin]        9216 B
    __shared__ unsigned int   kvb[32 * KVSTR];   // k(lo16)|v(hi16) [ch][pos] 18560 B
    __shared__ unsigned short qs[32 * 64];       // bf16 q, [ch][pixel]       4096 B

    const int tid = threadIdx.x;
    const int g = blockIdx.y, b = blockIdx.z;
    const int h0 = (blockIdx.x / 12) * 8;
    const int w0 = (blockIdx.x % 12) * 8;
    const float* xg = x + (size_t)(b * 128 + g * 32) * (HW * HW);

    // ---- Phase 1: coalesced staging. Per (ch,row): 4 aligned float4 loads
    //      covering cols [wA, wA+16); 12 region cols written, rest dropped. ----
    const int wA   = min(max(w0 - 4, 0), 80);
    const int colB = wA - w0 + 2;                // region col of first loaded float
    #pragma unroll
    for (int it = 0; it < 6; it++) {
        int idx = it * 256 + tid;                // 1536 = 32ch x 12row x 4seg
        int seg = idx & 3;
        int pr  = idx >> 2;
        int ch  = pr & 31;
        int row = pr >> 5;
        int iy  = refl(h0 + row - 2);
        const float4v f4 = *(const float4v*)(xg + ch * (HW * HW) + iy * HW + wA + seg * 4);
        int col0 = colB + seg * 4;
        #pragma unroll
        for (int e = 0; e < 4; e++) {
            int col = col0 + e;
            if (col >= 0 && col < RG)
                xs[(row * RG + col) * 32 + ch] = (unsigned short)bfr(f4[e]);
        }
    }

    // ---- Weight B-fragments (global loads in flight across the barrier) ----
    const int wid  = tid >> 6;
    const int lane = tid & 63;
    const int n0   = wid * 8;          // this wave's channel base
    const int col  = lane & 15;        // MFMA n / m index
    const int quad = lane >> 4;        // 0..3
    const int koff = quad * 8;         // K offset of this lane's 8 bf16

    const float* wrow = (col < 8) ? (wk + (g * 32 + n0 + col) * 32)
                                  : (wv + (g * 32 + n0 + col - 8) * 32);
    short8 bkv;
    #pragma unroll
    for (int j = 0; j < 8; j++)
        ((unsigned short*)&bkv)[j] = (unsigned short)bfr(wrow[koff + j]);

    short8 bq = {0, 0, 0, 0, 0, 0, 0, 0};   // cols 8-15 zero
    if (col < 8) {
        const float* qr = wq + (g * 32 + n0 + col) * 32;
        #pragma unroll
        for (int j = 0; j < 8; j++)
            ((unsigned short*)&bq)[j] = (unsigned short)bfr(qr[koff + j]);
    }

    // ---- Reflect halo columns for edge tiles (in-LDS copy) ----
    if (w0 == 0 || w0 == 88) {
        __syncthreads();                         // staging writes visible
        const int left = (w0 == 0);
        for (int it = 0; it < 3; it++) {
            int idx = it * 256 + tid;            // 768 = 32ch x 12row x 2cols
            int ch  = idx & 31;
            int rr  = idx >> 5;                  // 0..23
            int row = rr >> 1, wc = rr & 1;
            int dstc = left ? wc : (10 + wc);    // L: {0,1}  R: {10,11}
            int srcc = left ? (4 - wc) : (8 - wc); // L: {4,3} R: {8,7}
            xs[(row * RG + dstc) * 32 + ch] = xs[(row * RG + srcc) * 32 + ch];
        }
    }
    __syncthreads();

    // ---- Phase 2a: k,v conv — 9 MFMAs cover 144 positions x 16 (k8+v8) ----
    #pragma unroll
    for (int t = 0; t < 9; t++) {
        int p = t * 16 + col;                       // A row m -> region pos
        short8 a = *(const short8*)&xs[p * 32 + koff];
        float4v d = {0.f, 0.f, 0.f, 0.f};
        d = __builtin_amdgcn_mfma_f32_16x16x32_bf16(a, bkv, d, 0, 0, 0);
        // D: col=lane&15 (ch/type), rows = quad*4 + r (pos)
        int c = n0 + (col & 7);
        unsigned short* dst0 = (unsigned short*)&kvb[c * KVSTR + t * 16 + quad * 4];
        int half = (col < 8) ? 0 : 1;               // k -> lo16, v -> hi16
        #pragma unroll
        for (int r = 0; r < 4; r++)
            dst0[2 * r + half] = (unsigned short)bfr(d[r]);
    }

    // ---- Phase 2b: q conv — 4 MFMAs over the 64 center pixels ----
    #pragma unroll
    for (int t = 0; t < 4; t++) {
        int mp = t * 16 + col;                      // center pixel id 0..63
        int p  = ((mp >> 3) + 2) * RG + (mp & 7) + 2;
        short8 a = *(const short8*)&xs[p * 32 + koff];
        float4v d = {0.f, 0.f, 0.f, 0.f};
        d = __builtin_amdgcn_mfma_f32_16x16x32_bf16(a, bq, d, 0, 0, 0);
        if (col < 8) {
            unsigned int* dst = (unsigned int*)&qs[(n0 + col) * 64 + t * 16 + quad * 4];
            unsigned int u0 = __float_as_uint(d[0]) + 0x8000u;
            unsigned int u1 = __float_as_uint(d[1]) + 0x8000u;
            unsigned int u2 = __float_as_uint(d[2]) + 0x8000u;
            unsigned int u3 = __float_as_uint(d[3]) + 0x8000u;
            dst[0] = __builtin_amdgcn_perm(u1, u0, 0x07060302); // hi16(u0)|hi16(u1)<<16
            dst[1] = __builtin_amdgcn_perm(u3, u2, 0x07060302);
        }
    }

    __syncthreads();

    // ---- Phase 3: 25-tap softmax attention; lane = pixel, 8 channels ----
    const int ty = lane >> 3, tx = lane & 7;
    float* outp = out + (size_t)((b * 128 + g * 32 + n0) * HW + (h0 + ty)) * HW + (w0 + tx);
    for (int n = 0; n < 8; n++) {
        int c = n0 + n;
        float q = __uint_as_float((unsigned int)qs[c * 64 + lane] << 16) * 1.44269504f;
        float den = 0.f, num = 0.f;
        #pragma unroll
        for (int dy = 0; dy < 5; dy++) {
            const unsigned int* rowp = &kvb[c * KVSTR + (ty + dy) * RG + tx];
            #pragma unroll
            for (int dx = 0; dx < 5; dx++) {
                unsigned int u = rowp[dx];
                float kf = __uint_as_float(u << 16);
                float vf = __uint_as_float(u & 0xffff0000u);
                float e;
                asm("v_exp_f32 %0, %1" : "=v"(e) : "v"(q * kf));  // 2^x
                den += e;
                num = fmaf(e, vf, num);
            }
        }
        outp[n * (HW * HW)] = num * __builtin_amdgcn_rcpf(den);
    }
}

extern "C" void kernel_launch(void* const* d_in, const int* in_sizes, int n_in,
                              void* d_out, int out_size, void* d_ws, size_t ws_size,
                              hipStream_t stream) {
    const float* x  = (const float*)d_in[0];
    const float* wq = (const float*)d_in[1];
    const float* wk = (const float*)d_in[2];
    const float* wv = (const float*)d_in[3];
    float* out = (float*)d_out;

    dim3 grid(144, 4, 2);   // (spatial tiles, groups, batch)
    fused_attn<<<grid, 256, 0, stream>>>(x, wq, wk, wv, out);
}